// Round 1
// baseline (96245.361 us; speedup 1.0000x reference)
//
#include <hip/hip_runtime.h>
#include <math.h>

// Problem constants
#define Lz   2
#define Bz   32
#define Hz   512
#define Vz   32000
#define Tz   128
#define Gz   250        // persistent blocks
#define VBz  128        // vocab per block = 32000/250
#define NTz  512        // threads per block
#define BHz  (Bz*Hz)
#define LBHz (Lz*BHz)

// Workspace layout (byte offsets)
#define WS_BAR   0                       // unsigned[16]: grp[8], master@[8], gen@[9]
#define WS_ASUM  64                      // float[8][32]
#define WS_AMAX  1088                    // ull[8][32]
#define WS_H     3200                    // float[2][L][B][H]  (ping-pong)
#define WS_C     (WS_H + 2*LBHz*4)       // float[L][B][H]

__device__ __forceinline__ float sigmf(float x) { return 1.0f / (1.0f + expf(-x)); }

// Coherent (agent-scope, relaxed) scalar accesses: cross-XCD visible without
// any cache-invalidating fences, so read-only weights stay L2-resident.
__device__ __forceinline__ float cload(const float* p) {
  return __hip_atomic_load(p, __ATOMIC_RELAXED, __HIP_MEMORY_SCOPE_AGENT);
}
__device__ __forceinline__ void cstore(float* p, float v) {
  __hip_atomic_store(p, v, __ATOMIC_RELAXED, __HIP_MEMORY_SCOPE_AGENT);
}

__device__ __forceinline__ unsigned long long packlm(float x, int v) {
  unsigned u = __float_as_uint(x);
  u = (u & 0x80000000u) ? ~u : (u | 0x80000000u);   // order-preserving map
  return ((unsigned long long)u << 32) | (unsigned)(Vz - 1 - v);  // lower v wins ties
}

// Two-level grid barrier. No acquire/release *fences* (would invalidate L2);
// ordering comes from __syncthreads() vmcnt drains + single coherence point.
__device__ __forceinline__ void grid_barrier(unsigned* bar, int bid) {
  __syncthreads();
  if (threadIdx.x == 0) {
    unsigned* grp    = bar;
    unsigned* master = bar + 8;
    unsigned* gen    = bar + 9;
    unsigned g = __hip_atomic_load(gen, __ATOMIC_RELAXED, __HIP_MEMORY_SCOPE_AGENT);
    const int gi = bid & 7;
    const unsigned gsz = (unsigned)(Gz >> 3) + (((unsigned)gi < (Gz & 7u)) ? 1u : 0u);
    unsigned prev = __hip_atomic_fetch_add(&grp[gi], 1u, __ATOMIC_RELAXED, __HIP_MEMORY_SCOPE_AGENT);
    if (prev == gsz - 1u) {
      __hip_atomic_store(&grp[gi], 0u, __ATOMIC_RELAXED, __HIP_MEMORY_SCOPE_AGENT);
      // RELEASE orders the group-counter reset before the master bump
      unsigned pm = __hip_atomic_fetch_add(master, 1u, __ATOMIC_RELEASE, __HIP_MEMORY_SCOPE_AGENT);
      if (pm == 7u) {
        __hip_atomic_store(master, 0u, __ATOMIC_RELAXED, __HIP_MEMORY_SCOPE_AGENT);
        __hip_atomic_store(gen, g + 1u, __ATOMIC_RELEASE, __HIP_MEMORY_SCOPE_AGENT);
      }
    }
    while (__hip_atomic_load(gen, __ATOMIC_RELAXED, __HIP_MEMORY_SCOPE_AGENT) == g) {
      __builtin_amdgcn_s_sleep(1);
    }
  }
  __syncthreads();
}

// One LSTM layer: 512 threads compute 16 gate-rows x 32 batch for this block's
// 4 hidden indices; then 128 threads do the cell update.
template<bool RELU>
__device__ __forceinline__ void lstm_layer(
    int tid, int h0,
    const float* __restrict__ xrow,       // per-thread input row [H]
    const float* __restrict__ hrow,       // per-thread h_prev row [H]
    const float* __restrict__ wi,         // W_ih row [H]
    const float* __restrict__ wh,         // W_hh row [H]
    float bias,
    float* __restrict__ cbase,            // c buffer for this layer [B*H]
    float* __restrict__ hbase,            // h_new for this layer [B*H]
    float (*s_gates)[Bz])
{
  const int b = tid & 31, r = tid >> 5;   // r in 0..15 : row = gate*4 + hl
  float a1 = 0.f, a2 = 0.f;
  for (int k = 0; k < Hz; k += 4) {
    float x0, x1, x2, x3;
    if (RELU) {
      float4 xv = *(const float4*)(xrow + k);   // embedding: read-only, cached
      x0 = fmaxf(xv.x, 0.f); x1 = fmaxf(xv.y, 0.f);
      x2 = fmaxf(xv.z, 0.f); x3 = fmaxf(xv.w, 0.f);
    } else {
      x0 = cload(xrow + k);     x1 = cload(xrow + k + 1);
      x2 = cload(xrow + k + 2); x3 = cload(xrow + k + 3);
    }
    float4 wv = *(const float4*)(wi + k);
    a1 += x0 * wv.x + x1 * wv.y + x2 * wv.z + x3 * wv.w;
    float h0v = cload(hrow + k),     h1v = cload(hrow + k + 1);
    float h2v = cload(hrow + k + 2), h3v = cload(hrow + k + 3);
    float4 wv2 = *(const float4*)(wh + k);
    a2 += h0v * wv2.x + h1v * wv2.y + h2v * wv2.z + h3v * wv2.w;
  }
  s_gates[r][b] = a1 + a2 + bias;
  __syncthreads();
  if (tid < 4 * Bz) {
    const int b2 = tid & 31, hl2 = tid >> 5;      // hl2 in 0..3
    float gi = s_gates[hl2][b2];
    float gf = s_gates[4 + hl2][b2];
    float gG = s_gates[8 + hl2][b2];
    float go = s_gates[12 + hl2][b2];
    const int ci = b2 * Hz + h0 + hl2;
    float c_old = cload(cbase + ci);
    float cn = sigmf(gf) * c_old + sigmf(gi) * tanhf(gG);
    cstore(cbase + ci, cn);
    cstore(hbase + ci, sigmf(go) * tanhf(cn));
  }
}

__global__ void rnn_init(const float* __restrict__ enc, float* __restrict__ ws) {
  int i = blockIdx.x * blockDim.x + threadIdx.x;   // 64*512 = 32768 threads
  float* hs = (float*)((char*)ws + WS_H);
  float* cs = (float*)((char*)ws + WS_C);
  if (i < LBHz) { hs[i] = enc[i]; cs[i] = 0.f; }   // h0 = encoder_hidden, c0 = 0
  if (i < 256) {
    ((float*)((char*)ws + WS_ASUM))[i] = 0.f;
    ((unsigned long long*)((char*)ws + WS_AMAX))[i] = 0ull;
  }
  if (i < 16) ((unsigned*)ws)[i] = 0u;             // barrier state
}

__global__ __launch_bounds__(NTz, 4) void rnn_decode(
    const float* __restrict__ emb,
    const float* __restrict__ Wih,
    const float* __restrict__ Whh,
    const float* __restrict__ bih,
    const float* __restrict__ bhh,
    const float* __restrict__ Wout,
    const float* __restrict__ bout,
    float* __restrict__ out,
    float* __restrict__ ws)
{
  const int tid = threadIdx.x;
  const int bid = blockIdx.x;

  unsigned* bar = (unsigned*)ws;
  float* acc_sum = (float*)((char*)ws + WS_ASUM);
  unsigned long long* acc_max = (unsigned long long*)((char*)ws + WS_AMAX);
  float* hbufs = (float*)((char*)ws + WS_H);
  float* cbuf  = (float*)((char*)ws + WS_C);

  __shared__ float lds_logits[Bz * 129];   // padded: bank-conflict-free
  __shared__ float s_logZ[Bz];
  __shared__ int   s_tok[Bz];
  __shared__ float s_gates[16][Bz];
  __shared__ unsigned long long s_pmax[16][Bz];
  __shared__ float s_psum[16][Bz];

  const int v0 = bid * VBz;

  for (int t = 0; t < Tz; ++t) {
    float* h_old = hbufs + (t & 1) * LBHz;
    float* h_new = hbufs + ((t + 1) & 1) * LBHz;

    //---------------- P1: decode token, write logp(t-1), LSTM layer 0 ------
    if (t == 0) {
      if (tid < Bz) s_tok[tid] = 1;   // SOS
    } else {
      if (tid < Bz) {
        float s = 0.f;
        #pragma unroll
        for (int g = 0; g < 8; ++g)
          s += __hip_atomic_load(&acc_sum[g * Bz + tid], __ATOMIC_RELAXED, __HIP_MEMORY_SCOPE_AGENT);
        s_logZ[tid] = logf(s);
      } else if (tid < 2 * Bz) {
        int b = tid - Bz;
        unsigned long long m = 0ull;
        #pragma unroll
        for (int g = 0; g < 8; ++g) {
          unsigned long long x = __hip_atomic_load(&acc_max[g * Bz + b], __ATOMIC_RELAXED, __HIP_MEMORY_SCOPE_AGENT);
          m = (x > m) ? x : m;
        }
        s_tok[b] = (Vz - 1) - (int)(unsigned)(m & 0xFFFFFFFFull);
      }
    }
    __syncthreads();

    if (t > 0) {
      // logp(t-1) for this block's vocab chunk (kept in LDS across barrier)
      #pragma unroll
      for (int i = 0; i < 2; ++i) {
        int pos = i * (NTz * 4) + tid * 4;      // 0..4095 step 4
        int b = pos >> 7, v = pos & 127;
        float lz = s_logZ[b];
        float4 rr;
        rr.x = lds_logits[b * 129 + v]     - lz;
        rr.y = lds_logits[b * 129 + v + 1] - lz;
        rr.z = lds_logits[b * 129 + v + 2] - lz;
        rr.w = lds_logits[b * 129 + v + 3] - lz;
        *(float4*)(out + (size_t)b * (Tz * Vz) + (size_t)(t - 1) * Vz + v0 + v) = rr;
      }
    }

    if (bid < 128) {
      const int b = tid & 31, r = tid >> 5;
      const int gg = r >> 2, hl = r & 3;
      const int h0 = bid << 2;
      const int j = gg * Hz + h0 + hl;
      lstm_layer<true>(tid, h0,
          emb + (size_t)s_tok[b] * Hz,
          h_old + b * Hz,
          Wih + (size_t)j * Hz,
          Whh + (size_t)j * Hz,
          bih[j] + bhh[j],
          cbuf, h_new, s_gates);
    }
    grid_barrier(bar, bid);

    //---------------- P2: LSTM layer 1; zero accumulators ------------------
    if (bid < 128) {
      const int b = tid & 31, r = tid >> 5;
      const int gg = r >> 2, hl = r & 3;
      const int h0 = bid << 2;
      const int j = gg * Hz + h0 + hl;
      lstm_layer<false>(tid, h0,
          h_new + b * Hz,                       // input = fresh h1
          h_old + BHz + b * Hz,
          Wih + (size_t)(4 * Hz) * Hz + (size_t)j * Hz,
          Whh + (size_t)(4 * Hz) * Hz + (size_t)j * Hz,
          bih[4 * Hz + j] + bhh[4 * Hz + j],
          cbuf + BHz, h_new + BHz, s_gates);
    } else if (bid == 200) {
      if (tid < 256)
        __hip_atomic_store(&acc_sum[tid], 0.f, __ATOMIC_RELAXED, __HIP_MEMORY_SCOPE_AGENT);
      else if (tid < 512)
        __hip_atomic_store(&acc_max[tid - 256], 0ull, __ATOMIC_RELAXED, __HIP_MEMORY_SCOPE_AGENT);
    }
    grid_barrier(bar, bid);

    //---------------- P3: vocab projection + softmax partials --------------
    {
      const int w = tid >> 6, lane = tid & 63;
      const int b = lane & 31, vh = lane >> 5;
      const float* h2p = h_new + BHz + b * Hz;
      float acc[8];
      #pragma unroll
      for (int vi = 0; vi < 8; ++vi) acc[vi] = 0.f;
      for (int kc = 0; kc < 16; ++kc) {
        float hreg[32];
        #pragma unroll
        for (int q = 0; q < 32; ++q) hreg[q] = cload(h2p + kc * 32 + q);
        #pragma unroll
        for (int vi = 0; vi < 8; ++vi) {
          const int v = v0 + w * 16 + vi * 2 + vh;
          const float4* wp4 = (const float4*)(Wout + (size_t)v * Hz + kc * 32);
          #pragma unroll
          for (int q = 0; q < 8; ++q) {
            float4 wv = wp4[q];
            acc[vi] += hreg[4*q] * wv.x + hreg[4*q+1] * wv.y
                     + hreg[4*q+2] * wv.z + hreg[4*q+3] * wv.w;
          }
        }
      }
      #pragma unroll
      for (int vi = 0; vi < 8; ++vi) {
        int vl = w * 16 + vi * 2 + vh;
        lds_logits[b * 129 + vl] = acc[vi] + bout[v0 + vl];
      }
    }
    __syncthreads();
    {
      const int b2 = tid & 31, ch = tid >> 5;   // 16 chunks of 8 vocab
      float m = -3.0e38f; int argv = 0; float s = 0.f;
      #pragma unroll
      for (int u = 0; u < 8; ++u) {
        int vl = ch * 8 + u;
        float x = lds_logits[b2 * 129 + vl];
        s += expf(x);                            // fixed offset 0: |logit| is O(1..20), safe
        if (x > m) { m = x; argv = vl; }
      }
      s_pmax[ch][b2] = packlm(m, v0 + argv);
      s_psum[ch][b2] = s;
    }
    __syncthreads();
    if (tid < Bz) {
      unsigned long long m = 0ull; float s = 0.f;
      #pragma unroll
      for (int ch = 0; ch < 16; ++ch) {
        unsigned long long x = s_pmax[ch][tid];
        m = (x > m) ? x : m;
        s += s_psum[ch][tid];
      }
      atomicAdd(&acc_sum[(bid & 7) * Bz + tid], s);
      atomicMax(&acc_max[(bid & 7) * Bz + tid], m);
    }
    grid_barrier(bar, bid);
  }

  //---------------- final: logp(T-1), hT, cT --------------------------------
  if (tid < Bz) {
    float s = 0.f;
    #pragma unroll
    for (int g = 0; g < 8; ++g)
      s += __hip_atomic_load(&acc_sum[g * Bz + tid], __ATOMIC_RELAXED, __HIP_MEMORY_SCOPE_AGENT);
    s_logZ[tid] = logf(s);
  }
  __syncthreads();
  #pragma unroll
  for (int i = 0; i < 2; ++i) {
    int pos = i * (NTz * 4) + tid * 4;
    int b = pos >> 7, v = pos & 127;
    float lz = s_logZ[b];
    float4 rr;
    rr.x = lds_logits[b * 129 + v]     - lz;
    rr.y = lds_logits[b * 129 + v + 1] - lz;
    rr.z = lds_logits[b * 129 + v + 2] - lz;
    rr.w = lds_logits[b * 129 + v + 3] - lz;
    *(float4*)(out + (size_t)b * (Tz * Vz) + (size_t)(Tz - 1) * Vz + v0 + v) = rr;
  }
  if (bid >= 128 && bid < 144) {
    // final h is in buffer 0 (T even); c is single-buffered
    const float* hfin = hbufs;
    int base = (bid - 128) * NTz + tid;      // 0..8191
    #pragma unroll
    for (int q = 0; q < 8; ++q) {
      int idx = base * 8 + q;                // 0..65535
      float val = (idx < LBHz) ? cload(hfin + idx) : cload(cbuf + (idx - LBHz));
      out[(size_t)Bz * Tz * Vz + idx] = val;
    }
  }
}

extern "C" void kernel_launch(void* const* d_in, const int* in_sizes, int n_in,
                              void* d_out, int out_size, void* d_ws, size_t ws_size,
                              hipStream_t stream) {
  (void)in_sizes; (void)n_in; (void)out_size; (void)ws_size;
  const float* enc  = (const float*)d_in[0];
  const float* emb  = (const float*)d_in[1];
  const float* Wih  = (const float*)d_in[2];
  const float* Whh  = (const float*)d_in[3];
  const float* bih  = (const float*)d_in[4];
  const float* bhh  = (const float*)d_in[5];
  const float* Wout = (const float*)d_in[6];
  const float* bout = (const float*)d_in[7];
  float* out = (float*)d_out;
  float* ws  = (float*)d_ws;

  rnn_init<<<64, 512, 0, stream>>>(enc, ws);
  rnn_decode<<<Gz, NTz, 0, stream>>>(emb, Wih, Whh, bih, bhh, Wout, bout, out, ws);
}

// Round 3
// 17326.878 us; speedup vs baseline: 5.5547x; 5.5547x over previous
//
#include <hip/hip_runtime.h>
#include <math.h>

#define Gz   250
#define NTz  512
#define Bz   32
#define Hz   512
#define Vz   32000
#define Tz   128
#define VBz  128
#define BHz  (Bz*Hz)
#define LBHz (2*BHz)
#define BTVz ((size_t)Bz*(size_t)Tz*(size_t)Vz)

// workspace byte offsets
#define WS_BAR  0         // unsigned, grp[i] at [i*32], master at [256], gen at [257]
#define WS_ASUM 2048      // float[64][32]
#define WS_AMAX 10240     // ull[64][32]
#define WS_H    26624     // float[2 parity][2 layer][32][512]

// LDS byte offsets (dynamic)
#define L_HSA    0         // float[32][512] swizzled
#define L_HSB    65536     // float[32][512] swizzled
#define L_LOGITS 131072    // float[32*129]
#define L_SPART  131072    // overlay: float[16*32*8]
#define L_PMAX   147584    // ull[16*32]
#define L_PSUM   151680    // float[16*32]
#define L_REDM   153728    // ull[8*32]
#define L_REDS   155776    // float[8*32]
#define L_BIAS   156800    // float[16]
#define L_LOGZ   156864    // float[32]
#define L_TOK    156992    // int[32]
#define L_C      157120    // float[2][4][32]
#define L_TOTAL  158144

typedef unsigned long long ull;
typedef float f32x4 __attribute__((ext_vector_type(4)));

__device__ __forceinline__ float sigmf(float x) { return 1.0f / (1.0f + expf(-x)); }

__device__ __forceinline__ ull bp8(const float* p) {   // coherent 8B load
  return __hip_atomic_load((const ull*)p, __ATOMIC_RELAXED, __HIP_MEMORY_SCOPE_AGENT);
}
__device__ __forceinline__ void cstore(float* p, float v) {  // write-through 4B store
  __hip_atomic_store(p, v, __ATOMIC_RELAXED, __HIP_MEMORY_SCOPE_AGENT);
}
__device__ __forceinline__ ull packlm(float x, int v) {
  unsigned u = __float_as_uint(x);
  u = (u & 0x80000000u) ? ~u : (u | 0x80000000u);
  return ((ull)u << 32) | (unsigned)(Vz - 1 - v);   // lower v wins ties (np.argmax first-max)
}
// swizzled float index into [32][512] LDS tile: rows 16B-aligned, b-indexed reads 2-way max
__device__ __forceinline__ int hoff(int b, int k) { return (b << 9) + (k ^ ((b & 15) << 2)); }

__device__ __forceinline__ void grid_barrier(unsigned* bar, int bid) {
  __syncthreads();
  if (threadIdx.x == 0) {
    unsigned* gen = bar + 257;
    unsigned g = __hip_atomic_load(gen, __ATOMIC_RELAXED, __HIP_MEMORY_SCOPE_AGENT);
    const int gi = bid & 7;
    const unsigned gsz = (gi < 2) ? 32u : 31u;      // 250 = 2*32 + 6*31
    unsigned prev = __hip_atomic_fetch_add(&bar[gi * 32], 1u, __ATOMIC_RELAXED, __HIP_MEMORY_SCOPE_AGENT);
    if (prev == gsz - 1u) {
      __hip_atomic_store(&bar[gi * 32], 0u, __ATOMIC_RELAXED, __HIP_MEMORY_SCOPE_AGENT);
      unsigned pm = __hip_atomic_fetch_add(&bar[256], 1u, __ATOMIC_RELEASE, __HIP_MEMORY_SCOPE_AGENT);
      if (pm == 7u) {
        __hip_atomic_store(&bar[256], 0u, __ATOMIC_RELAXED, __HIP_MEMORY_SCOPE_AGENT);
        __hip_atomic_store(gen, g + 1u, __ATOMIC_RELEASE, __HIP_MEMORY_SCOPE_AGENT);
      }
    }
    while (__hip_atomic_load(gen, __ATOMIC_RELAXED, __HIP_MEMORY_SCOPE_AGENT) == g)
      __builtin_amdgcn_s_sleep(1);
  }
  __syncthreads();
}

// stage [32][512] floats from coherent global into swizzled LDS tile (coalesced 8B loads)
__device__ __forceinline__ void stage_rows(const float* __restrict__ src, float* lds, int tid) {
  #pragma unroll
  for (int it = 0; it < 16; ++it) {
    int u = it * NTz + tid;
    int f = u << 1;
    int b = f >> 9, k = f & 511;
    ull v = bp8(src + f);
    *(ull*)(lds + hoff(b, k)) = v;
  }
}

// one LSTM layer: 512 threads = 2 rowgroups x 8 kq x 32 b. Each thread: 8 gate-rows
// over a 64-wide k slice. x/h from LDS (or emb), W normal cached loads.
template<bool X_FROM_EMB>
__device__ __forceinline__ void lstm_phase(
    int tid, int hblk,
    const float* __restrict__ emb, const int* s_tok_,
    const float* xlds, const float* hlds,
    const float* __restrict__ Wih, const float* __restrict__ Whh,   // layer bases [2048][512]
    const float* __restrict__ bih, const float* __restrict__ bhh,   // layer bases [2048]
    float* s_part_, float* s_bias_, float* c_l,                     // c_l: [4][32]
    float* hdst)                                                    // h_new layer base [32][512]
{
  if (tid < 16) {
    int gate = tid >> 2, hl = tid & 3;
    int j = gate * Hz + (hblk << 2) + hl;
    s_bias_[tid] = bih[j] + bhh[j];
  }
  const int b = tid & 31, kq = (tid >> 5) & 7, rp = tid >> 8;
  const int k0 = kq * 64;
  const int swz = (b & 15) << 2;

  const float* wiP[8]; const float* whP[8];
  #pragma unroll
  for (int r = 0; r < 8; ++r) {
    int row = rp * 8 + r; int gate = row >> 2, hl = row & 3;
    size_t j = (size_t)(gate * Hz + (hblk << 2) + hl) * Hz + k0;
    wiP[r] = Wih + j; whP[r] = Whh + j;
  }
  const float* xbase; const float* hbase = hlds + (b << 9);
  if (X_FROM_EMB) xbase = emb + (size_t)s_tok_[b] * Hz + k0;
  else            xbase = xlds + (b << 9);

  float acc[8];
  #pragma unroll
  for (int r = 0; r < 8; ++r) acc[r] = 0.f;

  #pragma unroll 2
  for (int c = 0; c < 64; c += 4) {
    float x0, x1, x2, x3;
    if (X_FROM_EMB) {
      float4 xv = *(const float4*)(xbase + c);
      x0 = fmaxf(xv.x, 0.f); x1 = fmaxf(xv.y, 0.f);
      x2 = fmaxf(xv.z, 0.f); x3 = fmaxf(xv.w, 0.f);
    } else {
      float4 xv = *(const float4*)(xbase + ((k0 + c) ^ swz));
      x0 = xv.x; x1 = xv.y; x2 = xv.z; x3 = xv.w;
    }
    float4 hv = *(const float4*)(hbase + ((k0 + c) ^ swz));
    #pragma unroll
    for (int r = 0; r < 8; ++r) {
      float4 wiv = *(const float4*)(wiP[r] + c);
      float4 whv = *(const float4*)(whP[r] + c);
      acc[r] += x0 * wiv.x + x1 * wiv.y + x2 * wiv.z + x3 * wiv.w
              + hv.x * whv.x + hv.y * whv.y + hv.z * whv.z + hv.w * whv.w;
    }
  }
  #pragma unroll
  for (int r = 0; r < 8; ++r)
    s_part_[((rp * 8 + r) * 32 + b) * 8 + kq] = acc[r];
  __syncthreads();
  {
    int row = tid >> 5, bb = tid & 31;
    float s = s_bias_[row];
    #pragma unroll
    for (int q = 0; q < 8; ++q) s += s_part_[(row * 32 + bb) * 8 + q];
    s_part_[(row * 32 + bb) * 8] = s;     // only this thread touched these 8 slots
  }
  __syncthreads();
  if (tid < 128) {
    int hl = tid >> 5, bb = tid & 31;
    float gi = s_part_[((0 * 4 + hl) * 32 + bb) * 8];
    float gf = s_part_[((1 * 4 + hl) * 32 + bb) * 8];
    float gg = s_part_[((2 * 4 + hl) * 32 + bb) * 8];
    float go = s_part_[((3 * 4 + hl) * 32 + bb) * 8];
    float c_old = c_l[hl * 32 + bb];
    float cn = sigmf(gf) * c_old + sigmf(gi) * tanhf(gg);
    c_l[hl * 32 + bb] = cn;
    cstore(hdst + bb * Hz + (hblk << 2) + hl, sigmf(go) * tanhf(cn));
  }
}

__device__ __forceinline__ void tok_reduce(int tid, float* acc_sum, ull* acc_max,
                                           float* redS, ull* redM, float* logZ, int* tok) {
  if (tid < 256) {
    int b = tid & 31, g = tid >> 5;
    float s = 0.f; ull m = 0ull;
    #pragma unroll
    for (int u = 0; u < 8; ++u) {
      int bk = g * 8 + u;
      s += __hip_atomic_load(&acc_sum[bk * Bz + b], __ATOMIC_RELAXED, __HIP_MEMORY_SCOPE_AGENT);
      ull x = __hip_atomic_load(&acc_max[bk * Bz + b], __ATOMIC_RELAXED, __HIP_MEMORY_SCOPE_AGENT);
      m = x > m ? x : m;
    }
    redS[g * Bz + b] = s; redM[g * Bz + b] = m;
  }
  __syncthreads();
  if (tid < 32) {
    float s = 0.f; ull m = 0ull;
    #pragma unroll
    for (int g = 0; g < 8; ++g) {
      s += redS[g * Bz + tid];
      ull x = redM[g * Bz + tid]; m = x > m ? x : m;
    }
    logZ[tid] = logf(s);
    tok[tid] = (Vz - 1) - (int)(unsigned)(m & 0xFFFFFFFFull);
  }
  __syncthreads();
}

__device__ __forceinline__ void write_logp(int tid, int v0, int tstep,
                                           const float* logits_, const float* logZ_, float* out) {
  #pragma unroll
  for (int i = 0; i < 2; ++i) {
    int pos = ((i * NTz) + tid) * 4;      // 0..4095
    int b = pos >> 7, v = pos & 127;
    float lz = logZ_[b];
    f32x4 rr;
    rr.x = logits_[b * 129 + v]     - lz;
    rr.y = logits_[b * 129 + v + 1] - lz;
    rr.z = logits_[b * 129 + v + 2] - lz;
    rr.w = logits_[b * 129 + v + 3] - lz;
    __builtin_nontemporal_store(rr,
        (f32x4*)(out + (size_t)b * ((size_t)Tz * Vz) + (size_t)tstep * Vz + v0 + v));
  }
}

__global__ void rnn_init(const float* __restrict__ enc, float* __restrict__ ws) {
  int i = blockIdx.x * blockDim.x + threadIdx.x;   // 32768 threads
  float* hs = (float*)((char*)ws + WS_H);
  if (i < LBHz) hs[i] = enc[i];
  if (i < 2048) {
    ((float*)((char*)ws + WS_ASUM))[i] = 0.f;
    ((ull*)((char*)ws + WS_AMAX))[i] = 0ull;
  }
  if (i < 512) ((unsigned*)ws)[i] = 0u;
}

__global__ __launch_bounds__(NTz, 2) void rnn_decode(
    const float* __restrict__ emb,  const float* __restrict__ Wih,
    const float* __restrict__ Whh,  const float* __restrict__ bih,
    const float* __restrict__ bhh,  const float* __restrict__ Wout,
    const float* __restrict__ bout, float* __restrict__ out,
    float* __restrict__ ws)
{
  extern __shared__ char smem[];
  const int tid = threadIdx.x;
  const int bid = blockIdx.x;

  unsigned* bar = (unsigned*)ws;
  float* acc_sum = (float*)((char*)ws + WS_ASUM);
  ull*   acc_max = (ull*)((char*)ws + WS_AMAX);
  float* hbufs   = (float*)((char*)ws + WS_H);

  float* hsA    = (float*)(smem + L_HSA);
  float* hsB    = (float*)(smem + L_HSB);
  float* logits = (float*)(smem + L_LOGITS);
  float* s_part = (float*)(smem + L_SPART);
  ull*   pmax   = (ull*)(smem + L_PMAX);
  float* psum   = (float*)(smem + L_PSUM);
  ull*   redM   = (ull*)(smem + L_REDM);
  float* redS   = (float*)(smem + L_REDS);
  float* s_bias = (float*)(smem + L_BIAS);
  float* s_logZ = (float*)(smem + L_LOGZ);
  int*   s_tok  = (int*)(smem + L_TOK);
  float* s_c    = (float*)(smem + L_C);

  const int v0 = bid * VBz;
  if (tid < 256) s_c[tid] = 0.f;
  __syncthreads();

  for (int t = 0; t < Tz; ++t) {
    float* h_old = hbufs + (t & 1) * LBHz;
    float* h_new = hbufs + ((t + 1) & 1) * LBHz;

    //---- P1: stage h0_old early; token decode; logp(t-1); LSTM layer 0 ----
    if (bid < 128) stage_rows(h_old, hsA, tid);
    if (t == 0) {
      if (tid < 32) s_tok[tid] = 1;   // SOS
    } else {
      tok_reduce(tid, acc_sum, acc_max, redS, redM, s_logZ, s_tok);
      write_logp(tid, v0, t - 1, logits, s_logZ, out);
    }
    __syncthreads();
    if (bid < 128)
      lstm_phase<true>(tid, bid, emb, s_tok, nullptr, hsA,
                       Wih, Whh, bih, bhh, s_part, s_bias, s_c, h_new);
    grid_barrier(bar, bid);

    //---- P2: LSTM layer 1 (x = fresh h1, h = h1_old); zero accumulators ----
    if (bid < 128) {
      stage_rows(h_new, hsB, tid);
      stage_rows(h_old + BHz, hsA, tid);
      __syncthreads();
      lstm_phase<false>(tid, bid, nullptr, nullptr, hsB, hsA,
                        Wih + (size_t)2048 * Hz, Whh + (size_t)2048 * Hz,
                        bih + 2048, bhh + 2048, s_part, s_bias, s_c + 128, h_new + BHz);
    } else if (bid == 128) {
      for (int u = tid; u < 2048; u += NTz) {
        __hip_atomic_store(&acc_sum[u], 0.f, __ATOMIC_RELAXED, __HIP_MEMORY_SCOPE_AGENT);
        __hip_atomic_store(&acc_max[u], 0ull, __ATOMIC_RELAXED, __HIP_MEMORY_SCOPE_AGENT);
      }
    }
    grid_barrier(bar, bid);

    //---- P3: vocab projection (8 rows/thread) + softmax partials ----
    stage_rows(h_new + BHz, hsA, tid);
    __syncthreads();
    {
      const int w = tid >> 6, lane = tid & 63;
      const int b = lane & 31, vh = lane >> 5;
      const int swz = (b & 15) << 2;
      const float* hrow = hsA + (b << 9);
      const float* wP[8];
      #pragma unroll
      for (int vi = 0; vi < 8; ++vi)
        wP[vi] = Wout + (size_t)(v0 + w * 16 + vi * 2 + vh) * Hz;
      float acc[8];
      #pragma unroll
      for (int vi = 0; vi < 8; ++vi) acc[vi] = 0.f;
      #pragma unroll 2
      for (int kc = 0; kc < 64; ++kc) {
        int k = kc * 8;
        float4 h0v = *(const float4*)(hrow + (k ^ swz));
        float4 h1v = *(const float4*)(hrow + ((k + 4) ^ swz));
        #pragma unroll
        for (int vi = 0; vi < 8; ++vi) {
          float4 w0 = *(const float4*)(wP[vi] + k);
          float4 w1 = *(const float4*)(wP[vi] + k + 4);
          acc[vi] += h0v.x * w0.x + h0v.y * w0.y + h0v.z * w0.z + h0v.w * w0.w
                   + h1v.x * w1.x + h1v.y * w1.y + h1v.z * w1.z + h1v.w * w1.w;
        }
      }
      #pragma unroll
      for (int vi = 0; vi < 8; ++vi) {
        int vl = w * 16 + vi * 2 + vh;
        logits[b * 129 + vl] = acc[vi] + bout[v0 + vl];
      }
    }
    __syncthreads();
    {
      const int b2 = tid & 31, ch = tid >> 5;   // 16 chunks x 8 vocab
      float m = -3.0e38f; int argv = 0; float s = 0.f;
      #pragma unroll
      for (int u = 0; u < 8; ++u) {
        int vl = ch * 8 + u;
        float x = logits[b2 * 129 + vl];
        s += expf(x);                            // offset-0 softmax: logits are O(1), safe
        if (x > m) { m = x; argv = vl; }
      }
      pmax[ch * 32 + b2] = packlm(m, v0 + argv);
      psum[ch * 32 + b2] = s;
    }
    __syncthreads();
    if (tid < 32) {
      ull m = 0ull; float s = 0.f;
      #pragma unroll
      for (int ch = 0; ch < 16; ++ch) {
        ull x = pmax[ch * 32 + tid]; m = x > m ? x : m;
        s += psum[ch * 32 + tid];
      }
      atomicAdd(&acc_sum[(bid & 63) * Bz + tid], s);
      atomicMax(&acc_max[(bid & 63) * Bz + tid], m);
    }
    grid_barrier(bar, bid);
  }

  //---- epilogue: logp(T-1), hT, cT ----
  tok_reduce(tid, acc_sum, acc_max, redS, redM, s_logZ, s_tok);
  write_logp(tid, v0, Tz - 1, logits, s_logZ, out);
  if (bid >= 128 && bid < 144) {
    int f = (bid - 128) * 2048 + tid * 4;       // hT: 32768 floats from parity-0 buffer
    ull a = bp8(hbufs + f), b = bp8(hbufs + f + 2);
    *(ull*)(out + BTVz + f) = a;
    *(ull*)(out + BTVz + f + 2) = b;
  }
  if (bid < 128 && tid < 256) {
    int l = tid >> 7, hl = (tid >> 5) & 3, bb = tid & 31;
    out[BTVz + LBHz + (size_t)l * BHz + (size_t)bb * Hz + (bid << 2) + hl] =
        s_c[l * 128 + hl * 32 + bb];
  }
}

extern "C" void kernel_launch(void* const* d_in, const int* in_sizes, int n_in,
                              void* d_out, int out_size, void* d_ws, size_t ws_size,
                              hipStream_t stream) {
  (void)in_sizes; (void)n_in; (void)out_size; (void)ws_size;
  const float* enc  = (const float*)d_in[0];
  const float* emb  = (const float*)d_in[1];
  const float* Wih  = (const float*)d_in[2];
  const float* Whh  = (const float*)d_in[3];
  const float* bih  = (const float*)d_in[4];
  const float* bhh  = (const float*)d_in[5];
  const float* Wout = (const float*)d_in[6];
  const float* bout = (const float*)d_in[7];
  float* out = (float*)d_out;
  float* ws  = (float*)d_ws;

  (void)hipFuncSetAttribute((const void*)rnn_decode,
                            hipFuncAttributeMaxDynamicSharedMemorySize, L_TOTAL);
  rnn_init<<<64, 512, 0, stream>>>(enc, ws);
  rnn_decode<<<Gz, NTz, L_TOTAL, stream>>>(emb, Wih, Whh, bih, bhh, Wout, bout, out, ws);
}

// Round 4
// 15884.012 us; speedup vs baseline: 6.0593x; 1.0908x over previous
//
#include <hip/hip_runtime.h>
#include <math.h>

#define Gz   250
#define NTz  512
#define Bz   32
#define Hz   512
#define Vz   32000
#define Tz   128
#define VBz  128
#define BHz  (Bz*Hz)
#define LBHz (2*BHz)
#define BTVz ((size_t)Bz*(size_t)Tz*(size_t)Vz)

// workspace byte offsets
#define WS_BAR  0         // unsigned, grp[i] at [i*32], master at [256], gen at [257]
#define WS_ASUM 2048      // float[64][32]
#define WS_AMAX 10240     // ull[64][32]
#define WS_H    26624     // float[2 parity][2 layer][32][512]

// LDS byte offsets (dynamic)
#define L_HSA    0         // float[32][512] (swizzled for LSTM; plain for P3 overlay)
#define L_HSB    65536     // float[32][512] swizzled
#define L_LOGITS 131072    // float[32*129]
#define L_SPART  131072    // overlay: float[16*32*8] (clobbers logits AFTER write_logp)
#define L_PMAX   147584    // ull[16*32]
#define L_PSUM   151680    // float[16*32]
#define L_REDM   153728    // ull[8*32]
#define L_REDS   155776    // float[8*32]
#define L_BIAS   156800    // float[16]
#define L_LOGZ   156864    // float[32]
#define L_TOK    156992    // int[32]
#define L_C      157120    // float[2][4][32]
#define L_TOTAL  158144

typedef unsigned long long ull;
typedef float f32x4 __attribute__((ext_vector_type(4)));
typedef float f32x2 __attribute__((ext_vector_type(2)));

__device__ __forceinline__ float sigmf(float x) { return 1.0f / (1.0f + expf(-x)); }

__device__ __forceinline__ ull bp8(const float* p) {   // coherent 8B load
  return __hip_atomic_load((const ull*)p, __ATOMIC_RELAXED, __HIP_MEMORY_SCOPE_AGENT);
}
__device__ __forceinline__ void cstore(float* p, float v) {  // write-through 4B store
  __hip_atomic_store(p, v, __ATOMIC_RELAXED, __HIP_MEMORY_SCOPE_AGENT);
}
__device__ __forceinline__ ull packlm(float x, int v) {
  unsigned u = __float_as_uint(x);
  u = (u & 0x80000000u) ? ~u : (u | 0x80000000u);
  return ((ull)u << 32) | (unsigned)(Vz - 1 - v);   // lower v wins ties (np.argmax first-max)
}
// swizzled float index into [32][512] LDS tile (LSTM tiles)
__device__ __forceinline__ int hoff(int b, int k) { return (b << 9) + (k ^ ((b & 15) << 2)); }

__device__ __forceinline__ void grid_barrier(unsigned* bar, int bid) {
  __syncthreads();
  if (threadIdx.x == 0) {
    unsigned* gen = bar + 257;
    unsigned g = __hip_atomic_load(gen, __ATOMIC_RELAXED, __HIP_MEMORY_SCOPE_AGENT);
    const int gi = bid & 7;
    const unsigned gsz = (gi < 2) ? 32u : 31u;      // 250 = 2*32 + 6*31
    unsigned prev = __hip_atomic_fetch_add(&bar[gi * 32], 1u, __ATOMIC_RELAXED, __HIP_MEMORY_SCOPE_AGENT);
    if (prev == gsz - 1u) {
      __hip_atomic_store(&bar[gi * 32], 0u, __ATOMIC_RELAXED, __HIP_MEMORY_SCOPE_AGENT);
      unsigned pm = __hip_atomic_fetch_add(&bar[256], 1u, __ATOMIC_RELEASE, __HIP_MEMORY_SCOPE_AGENT);
      if (pm == 7u) {
        __hip_atomic_store(&bar[256], 0u, __ATOMIC_RELAXED, __HIP_MEMORY_SCOPE_AGENT);
        __hip_atomic_store(gen, g + 1u, __ATOMIC_RELEASE, __HIP_MEMORY_SCOPE_AGENT);
      }
    }
    while (__hip_atomic_load(gen, __ATOMIC_RELAXED, __HIP_MEMORY_SCOPE_AGENT) == g)
      __builtin_amdgcn_s_sleep(1);
  }
  __syncthreads();
}

// stage [32][512] floats from coherent global into swizzled LDS tile
__device__ __forceinline__ void stage_rows(const float* __restrict__ src, float* lds, int tid) {
  #pragma unroll
  for (int it = 0; it < 16; ++it) {
    int f = (it * NTz + tid) << 1;
    int b = f >> 9, k = f & 511;
    ull v = bp8(src + f);
    *(ull*)(lds + hoff(b, k)) = v;
  }
}
// stage [32][512] floats into PLAIN LDS tile (P3: row-contiguous reads, no swizzle needed)
__device__ __forceinline__ void stage_plain(const float* __restrict__ src, float* lds, int tid) {
  #pragma unroll
  for (int it = 0; it < 16; ++it) {
    int f = (it * NTz + tid) << 1;
    ull v = bp8(src + f);
    *(ull*)(lds + f) = v;
  }
}

// one LSTM layer: 512 threads = 2 rowgroups x 8 kq x 32 b. Each thread: 8 gate-rows
// over a 64-wide k slice. x/h from LDS (or emb), W normal cached loads (L2-resident).
template<bool X_FROM_EMB>
__device__ __forceinline__ void lstm_phase(
    int tid, int hblk,
    const float* __restrict__ emb, const int* s_tok_,
    const float* xlds, const float* hlds,
    const float* __restrict__ Wih, const float* __restrict__ Whh,
    const float* __restrict__ bih, const float* __restrict__ bhh,
    float* s_part_, float* s_bias_, float* c_l,
    float* hdst)
{
  if (tid < 16) {
    int gate = tid >> 2, hl = tid & 3;
    int j = gate * Hz + (hblk << 2) + hl;
    s_bias_[tid] = bih[j] + bhh[j];
  }
  const int b = tid & 31, kq = (tid >> 5) & 7, rp = tid >> 8;
  const int k0 = kq * 64;
  const int swz = (b & 15) << 2;

  const float* wiP[8]; const float* whP[8];
  #pragma unroll
  for (int r = 0; r < 8; ++r) {
    int row = rp * 8 + r; int gate = row >> 2, hl = row & 3;
    size_t j = (size_t)(gate * Hz + (hblk << 2) + hl) * Hz + k0;
    wiP[r] = Wih + j; whP[r] = Whh + j;
  }
  const float* xbase; const float* hbase = hlds + (b << 9);
  if (X_FROM_EMB) xbase = emb + (size_t)s_tok_[b] * Hz + k0;
  else            xbase = xlds + (b << 9);

  float acc[8];
  #pragma unroll
  for (int r = 0; r < 8; ++r) acc[r] = 0.f;

  #pragma unroll 2
  for (int c = 0; c < 64; c += 4) {
    float x0, x1, x2, x3;
    if (X_FROM_EMB) {
      float4 xv = *(const float4*)(xbase + c);
      x0 = fmaxf(xv.x, 0.f); x1 = fmaxf(xv.y, 0.f);
      x2 = fmaxf(xv.z, 0.f); x3 = fmaxf(xv.w, 0.f);
    } else {
      float4 xv = *(const float4*)(xbase + ((k0 + c) ^ swz));
      x0 = xv.x; x1 = xv.y; x2 = xv.z; x3 = xv.w;
    }
    float4 hv = *(const float4*)(hbase + ((k0 + c) ^ swz));
    #pragma unroll
    for (int r = 0; r < 8; ++r) {
      float4 wiv = *(const float4*)(wiP[r] + c);
      float4 whv = *(const float4*)(whP[r] + c);
      acc[r] += x0 * wiv.x + x1 * wiv.y + x2 * wiv.z + x3 * wiv.w
              + hv.x * whv.x + hv.y * whv.y + hv.z * whv.z + hv.w * whv.w;
    }
  }
  #pragma unroll
  for (int r = 0; r < 8; ++r)
    s_part_[((rp * 8 + r) * 32 + b) * 8 + kq] = acc[r];
  __syncthreads();
  {
    int row = tid >> 5, bb = tid & 31;
    float s = s_bias_[row];
    #pragma unroll
    for (int q = 0; q < 8; ++q) s += s_part_[(row * 32 + bb) * 8 + q];
    s_part_[(row * 32 + bb) * 8] = s;
  }
  __syncthreads();
  if (tid < 128) {
    int hl = tid >> 5, bb = tid & 31;
    float gi = s_part_[((0 * 4 + hl) * 32 + bb) * 8];
    float gf = s_part_[((1 * 4 + hl) * 32 + bb) * 8];
    float gg = s_part_[((2 * 4 + hl) * 32 + bb) * 8];
    float go = s_part_[((3 * 4 + hl) * 32 + bb) * 8];
    float c_old = c_l[hl * 32 + bb];
    float cn = sigmf(gf) * c_old + sigmf(gi) * tanhf(gg);
    c_l[hl * 32 + bb] = cn;
    cstore(hdst + bb * Hz + (hblk << 2) + hl, sigmf(go) * tanhf(cn));
  }
}

__device__ __forceinline__ void tok_reduce(int tid, float* acc_sum, ull* acc_max,
                                           float* redS, ull* redM, float* logZ, int* tok) {
  if (tid < 256) {
    int b = tid & 31, g = tid >> 5;
    float s = 0.f; ull m = 0ull;
    #pragma unroll
    for (int u = 0; u < 8; ++u) {
      int bk = g * 8 + u;
      s += __hip_atomic_load(&acc_sum[bk * Bz + b], __ATOMIC_RELAXED, __HIP_MEMORY_SCOPE_AGENT);
      ull x = __hip_atomic_load(&acc_max[bk * Bz + b], __ATOMIC_RELAXED, __HIP_MEMORY_SCOPE_AGENT);
      m = x > m ? x : m;
    }
    redS[g * Bz + b] = s; redM[g * Bz + b] = m;
  }
  __syncthreads();
  if (tid < 32) {
    float s = 0.f; ull m = 0ull;
    #pragma unroll
    for (int g = 0; g < 8; ++g) {
      s += redS[g * Bz + tid];
      ull x = redM[g * Bz + tid]; m = x > m ? x : m;
    }
    logZ[tid] = logf(s);
    tok[tid] = (Vz - 1) - (int)(unsigned)(m & 0xFFFFFFFFull);
  }
  __syncthreads();
}

__device__ __forceinline__ void write_logp(int tid, int v0, int tstep,
                                           const float* logits_, const float* logZ_, float* out) {
  #pragma unroll
  for (int i = 0; i < 2; ++i) {
    int pos = ((i * NTz) + tid) * 4;      // 0..4095
    int b = pos >> 7, v = pos & 127;
    float lz = logZ_[b];
    f32x4 rr;
    rr.x = logits_[b * 129 + v]     - lz;
    rr.y = logits_[b * 129 + v + 1] - lz;
    rr.z = logits_[b * 129 + v + 2] - lz;
    rr.w = logits_[b * 129 + v + 3] - lz;
    __builtin_nontemporal_store(rr,
        (f32x4*)(out + (size_t)b * ((size_t)Tz * Vz) + (size_t)tstep * Vz + v0 + v));
  }
}

__global__ void rnn_init(const float* __restrict__ enc, float* __restrict__ ws) {
  int i = blockIdx.x * blockDim.x + threadIdx.x;   // 32768 threads
  float* hs = (float*)((char*)ws + WS_H);
  if (i < LBHz) hs[i] = enc[i];
  if (i < 2048) {
    ((float*)((char*)ws + WS_ASUM))[i] = 0.f;
    ((ull*)((char*)ws + WS_AMAX))[i] = 0ull;
  }
  if (i < 512) ((unsigned*)ws)[i] = 0u;
}

__global__ __launch_bounds__(NTz, 2) void rnn_decode(
    const float* __restrict__ emb,  const float* __restrict__ Wih,
    const float* __restrict__ Whh,  const float* __restrict__ bih,
    const float* __restrict__ bhh,  const float* __restrict__ Wout,
    const float* __restrict__ bout, float* __restrict__ out,
    float* __restrict__ ws)
{
  extern __shared__ char smem[];
  const int tid = threadIdx.x;
  const int bid = blockIdx.x;

  unsigned* bar = (unsigned*)ws;
  float* acc_sum = (float*)((char*)ws + WS_ASUM);
  ull*   acc_max = (ull*)((char*)ws + WS_AMAX);
  float* hbufs   = (float*)((char*)ws + WS_H);

  float* hsA    = (float*)(smem + L_HSA);
  float* hsB    = (float*)(smem + L_HSB);
  float* logits = (float*)(smem + L_LOGITS);
  float* s_part = (float*)(smem + L_SPART);
  ull*   pmax   = (ull*)(smem + L_PMAX);
  float* psum   = (float*)(smem + L_PSUM);
  ull*   redM   = (ull*)(smem + L_REDM);
  float* redS   = (float*)(smem + L_REDS);
  float* s_bias = (float*)(smem + L_BIAS);
  float* s_logZ = (float*)(smem + L_LOGZ);
  int*   s_tok  = (int*)(smem + L_TOK);
  float* s_c    = (float*)(smem + L_C);

  const int v0 = bid * VBz;
  if (tid < 256) s_c[tid] = 0.f;
  __syncthreads();

  //---- one-time: this block's W_out slice into registers -------------------
  // thread (vg,kq): rows v0+vg*4+r (r<4), ks = kq+16c (c<32) paired (ca,ca+8)
  const int vg = tid >> 4, kq = tid & 15;
  f32x2 w2[4][16];
  float b_r[4];
  #pragma unroll
  for (int r = 0; r < 4; ++r) {
    const float* wrow = Wout + (size_t)(v0 + (vg << 2) + r) * Hz + kq;
    #pragma unroll
    for (int p = 0; p < 16; ++p) {
      const int ca = (p < 8) ? p : p + 8;
      w2[r][p].x = wrow[ca << 4];
      w2[r][p].y = wrow[(ca + 8) << 4];
    }
    b_r[r] = bout[v0 + (vg << 2) + r];
  }

  for (int t = 0; t < Tz; ++t) {
    float* h_old = hbufs + (t & 1) * LBHz;
    float* h_new = hbufs + ((t + 1) & 1) * LBHz;

    //---- P1: stage h0_old; token decode; logp(t-1); LSTM layer 0 ----
    if (bid < 128) stage_rows(h_old, hsA, tid);
    if (t == 0) {
      if (tid < 32) s_tok[tid] = 1;   // SOS
    } else {
      tok_reduce(tid, acc_sum, acc_max, redS, redM, s_logZ, s_tok);
      write_logp(tid, v0, t - 1, logits, s_logZ, out);
    }
    __syncthreads();
    if (bid < 128)
      lstm_phase<true>(tid, bid, emb, s_tok, nullptr, hsA,
                       Wih, Whh, bih, bhh, s_part, s_bias, s_c, h_new);
    grid_barrier(bar, bid);

    //---- P2: LSTM layer 1; zero accumulators ----
    if (bid < 128) {
      stage_rows(h_new, hsB, tid);
      stage_rows(h_old + BHz, hsA, tid);
      __syncthreads();
      lstm_phase<false>(tid, bid, nullptr, nullptr, hsB, hsA,
                        Wih + (size_t)2048 * Hz, Whh + (size_t)2048 * Hz,
                        bih + 2048, bhh + 2048, s_part, s_bias, s_c + 128, h_new + BHz);
    } else if (bid == 128) {
      for (int u = tid; u < 2048; u += NTz) {
        __hip_atomic_store(&acc_sum[u], 0.f, __ATOMIC_RELAXED, __HIP_MEMORY_SCOPE_AGENT);
        __hip_atomic_store(&acc_max[u], 0ull, __ATOMIC_RELAXED, __HIP_MEMORY_SCOPE_AGENT);
      }
    }
    grid_barrier(bar, bid);

    //---- P3: stage h2 (plain tile); register-resident matvec; softmax partials ----
    stage_plain(h_new + BHz, hsA, tid);
    __syncthreads();
    {
      const float* hb0 = hsA + kq;
      #pragma unroll 2
      for (int b = 0; b < 32; ++b) {
        const float* hb = hb0 + (b << 9);
        f32x2 acc2[4];
        #pragma unroll
        for (int r = 0; r < 4; ++r) { acc2[r].x = 0.f; acc2[r].y = 0.f; }
        #pragma unroll
        for (int p = 0; p < 16; ++p) {
          const int ca = (p < 8) ? p : p + 8;
          f32x2 hv;
          hv.x = hb[ca << 4];
          hv.y = hb[(ca + 8) << 4];
          #pragma unroll
          for (int r = 0; r < 4; ++r) acc2[r] += w2[r][p] * hv;
        }
        #pragma unroll
        for (int r = 0; r < 4; ++r) {
          float a = acc2[r].x + acc2[r].y;
          a += __shfl_xor(a, 1);
          a += __shfl_xor(a, 2);
          a += __shfl_xor(a, 4);
          a += __shfl_xor(a, 8);
          if (kq == 0) logits[b * 129 + (vg << 2) + r] = a + b_r[r];
        }
      }
    }
    __syncthreads();
    {
      const int b2 = tid & 31, ch = tid >> 5;   // 16 chunks x 8 vocab
      float m = -3.0e38f; int argv = 0; float s = 0.f;
      #pragma unroll
      for (int u = 0; u < 8; ++u) {
        int vl = ch * 8 + u;
        float x = logits[b2 * 129 + vl];
        s += expf(x);                            // offset-0 softmax: logits are O(1), safe
        if (x > m) { m = x; argv = vl; }
      }
      pmax[ch * 32 + b2] = packlm(m, v0 + argv);
      psum[ch * 32 + b2] = s;
    }
    __syncthreads();
    if (tid < 32) {
      ull m = 0ull; float s = 0.f;
      #pragma unroll
      for (int ch = 0; ch < 16; ++ch) {
        ull x = pmax[ch * 32 + tid]; m = x > m ? x : m;
        s += psum[ch * 32 + tid];
      }
      atomicAdd(&acc_sum[(bid & 63) * Bz + tid], s);
      atomicMax(&acc_max[(bid & 63) * Bz + tid], m);
    }
    grid_barrier(bar, bid);
  }

  //---- epilogue: logp(T-1), hT, cT ----
  tok_reduce(tid, acc_sum, acc_max, redS, redM, s_logZ, s_tok);
  write_logp(tid, v0, Tz - 1, logits, s_logZ, out);
  if (bid >= 128 && bid < 144) {
    int f = (bid - 128) * 2048 + tid * 4;       // hT: 32768 floats from parity-0 buffer
    ull a = bp8(hbufs + f), b = bp8(hbufs + f + 2);
    *(ull*)(out + BTVz + f) = a;
    *(ull*)(out + BTVz + f + 2) = b;
  }
  if (bid < 128 && tid < 256) {
    int l = tid >> 7, hl = (tid >> 5) & 3, bb = tid & 31;
    out[BTVz + LBHz + (size_t)l * BHz + (size_t)bb * Hz + (bid << 2) + hl] =
        s_c[l * 128 + hl * 32 + bb];
  }
}

extern "C" void kernel_launch(void* const* d_in, const int* in_sizes, int n_in,
                              void* d_out, int out_size, void* d_ws, size_t ws_size,
                              hipStream_t stream) {
  (void)in_sizes; (void)n_in; (void)out_size; (void)ws_size;
  const float* enc  = (const float*)d_in[0];
  const float* emb  = (const float*)d_in[1];
  const float* Wih  = (const float*)d_in[2];
  const float* Whh  = (const float*)d_in[3];
  const float* bih  = (const float*)d_in[4];
  const float* bhh  = (const float*)d_in[5];
  const float* Wout = (const float*)d_in[6];
  const float* bout = (const float*)d_in[7];
  float* out = (float*)d_out;
  float* ws  = (float*)d_ws;

  (void)hipFuncSetAttribute((const void*)rnn_decode,
                            hipFuncAttributeMaxDynamicSharedMemorySize, L_TOTAL);
  rnn_init<<<64, 512, 0, stream>>>(enc, ws);
  rnn_decode<<<Gz, NTz, L_TOTAL, stream>>>(emb, Wih, Whh, bih, bhh, Wout, bout, out, ws);
}